// Round 6
// baseline (227.221 us; speedup 1.0000x reference)
//
#include <hip/hip_runtime.h>
#include <cmath>

#define NPTS 262144
#define NLVL 16
#define TBL  524288u
#define TMASK 524287u
#define TPB  512   // points per block (k2): 8 waves, 2 blocks/CU
#define NQ   7     // levels 0..6 oct-densified

typedef __attribute__((ext_vector_type(8))) short short8;
typedef __attribute__((ext_vector_type(4))) float f32x4;

struct ResArr { float r[NLVL]; };
struct QuadInfo { int off[NQ]; int dim[NQ]; int toff[NQ+1]; }; // off: oct entries; toff: build-thread prefix

__device__ __forceinline__ unsigned short f2bf(float f) {
    union { float f; unsigned u; } v; v.f = f;
    unsigned r = v.u + 0x7FFFu + ((v.u >> 16) & 1u);   // RNE
    return (unsigned short)(r >> 16);
}
__device__ __forceinline__ float blo(unsigned u) {
    union { unsigned v; float f; } x; x.v = u << 16; return x.f;
}
__device__ __forceinline__ float bhi(unsigned u) {
    union { unsigned v; float f; } x; x.v = u & 0xffff0000u; return x.f;
}
__device__ __forceinline__ unsigned packbf(float a, float b) {
    return (unsigned)f2bf(a) | ((unsigned)f2bf(b) << 16);
}

#define MFMA(a,b,c) __builtin_amdgcn_mfma_f32_16x16x32_bf16((a),(b),(c),0,0,0)

// ---------------------------------------------------------------------------
// Kernel 1 (fused): hash-grid encode for levels 7..15 + oct BUILD for levels
// 0..6 + weight/bias pack, one request stream.
// R6: build uses x-parity pair-loads too — one thread covers TWO cells
// (slabs x, x+1 for even x) with 4 float4 pair-gathers instead of 2x4 float2
// gathers: build req 5/cell -> 3/cell (2.72M -> 1.63M total, -6% of stream).
// ---------------------------------------------------------------------------
__global__ __launch_bounds__(256) void fused_encode_k(
    const float* __restrict__ coords,
    const float* __restrict__ emb,
    uint4* __restrict__ oct,
    unsigned* __restrict__ featws,
    const float* __restrict__ dw1, const float* __restrict__ db1,
    const float* __restrict__ dw2, const float* __restrict__ db2,
    const float* __restrict__ cw1, const float* __restrict__ cb1,
    const float* __restrict__ cw2, const float* __restrict__ cb2,
    const float* __restrict__ cw3, const float* __restrict__ cb3,
    const float* __restrict__ cw4, const float* __restrict__ cb4,
    unsigned short* __restrict__ wpk, float* __restrict__ bpk,
    ResArr res, QuadInfo qi, int ncb, int tailn)
{
    const int tid = threadIdx.x;
    const int b   = blockIdx.x;
    const int xcd = b & 7;
    const int s   = b >> 3;

    if (s < 1152) {
        // -------- hashed path (levels 7..15), x-parity pairing --------
        int l, p;
        if (s < 1024) {
            l = 7 + xcd;
            p = s * 256 + tid;
        } else {
            l = 15;
            p = xcd * 32768 + (s - 1024) * 256 + tid;
        }

        const float cx = coords[3*p], cy = coords[3*p+1], cz = coords[3*p+2];
        const float r = res.r[l];
        const float px = cx*r, py = cy*r, pz = cz*r;
        const float fpx = floorf(px), fpy = floorf(py), fpz = floorf(pz);
        const float fx = px-fpx, fy = py-fpy, fz = pz-fpz;
        const unsigned ix=(unsigned)fpx, iy=(unsigned)fpy, iz=(unsigned)fpz;
        const unsigned hy0=iy*2654435761u, hy1=(iy+1u)*2654435761u;
        const unsigned hz0=iz*805459861u,  hz1=(iz+1u)*805459861u;
        const unsigned base  = (unsigned)l * TBL;          // float2 units
        const unsigned base4 = (unsigned)l * (TBL >> 1);   // float4 units
        const float2* __restrict__ emb2 = (const float2*)emb;
        const float4* __restrict__ emb4 = (const float4*)emb;

        const unsigned m = ix ^ (ix + 1u);                 // 1 iff ix even
        const unsigned h00 = (ix^hy0^hz0) & TMASK;
        const unsigned h01 = (ix^hy0^hz1) & TMASK;
        const unsigned h10 = (ix^hy1^hz0) & TMASK;
        const unsigned h11 = (ix^hy1^hz1) & TMASK;

        // pair loads: float4 at h>>1 = entries {h&~1, h|1}
        const float4 p00 = emb4[base4 + (h00 >> 1)];
        const float4 p01 = emb4[base4 + (h01 >> 1)];
        const float4 p10 = emb4[base4 + (h10 >> 1)];
        const float4 p11 = emb4[base4 + (h11 >> 1)];

        // x0 corner = half selected by h&1; x1 corner = other half (iff m==1)
        float2 f000, f001, f010, f011, f100, f101, f110, f111;
        f000.x = (h00&1) ? p00.z : p00.x;  f000.y = (h00&1) ? p00.w : p00.y;
        f001.x = (h01&1) ? p01.z : p01.x;  f001.y = (h01&1) ? p01.w : p01.y;
        f010.x = (h10&1) ? p10.z : p10.x;  f010.y = (h10&1) ? p10.w : p10.y;
        f011.x = (h11&1) ? p11.z : p11.x;  f011.y = (h11&1) ? p11.w : p11.y;
        f100.x = (h00&1) ? p00.x : p00.z;  f100.y = (h00&1) ? p00.y : p00.w;
        f101.x = (h01&1) ? p01.x : p01.z;  f101.y = (h01&1) ? p01.y : p01.w;
        f110.x = (h10&1) ? p10.x : p10.z;  f110.y = (h10&1) ? p10.y : p10.w;
        f111.x = (h11&1) ? p11.x : p11.z;  f111.y = (h11&1) ? p11.y : p11.w;

        if (m != 1u) {
            // odd-x lanes: true x1 corners are h^m, not in the pair
            f100 = emb2[base + ((h00 ^ m) & TMASK)];
            f101 = emb2[base + ((h01 ^ m) & TMASK)];
            f110 = emb2[base + ((h10 ^ m) & TMASK)];
            f111 = emb2[base + ((h11 ^ m) & TMASK)];
        }

        const float wx0=1.f-fx, wy0=1.f-fy, wz0=1.f-fz;
        float o0, o1;
        o0 = wx0*wy0*wz0*f000.x;                 o1 = wx0*wy0*wz0*f000.y;
        o0 = fmaf(wx0*wy0*fz,  f001.x, o0);      o1 = fmaf(wx0*wy0*fz,  f001.y, o1);
        o0 = fmaf(wx0*fy*wz0,  f010.x, o0);      o1 = fmaf(wx0*fy*wz0,  f010.y, o1);
        o0 = fmaf(wx0*fy*fz,   f011.x, o0);      o1 = fmaf(wx0*fy*fz,   f011.y, o1);
        o0 = fmaf(fx*wy0*wz0,  f100.x, o0);      o1 = fmaf(fx*wy0*wz0,  f100.y, o1);
        o0 = fmaf(fx*wy0*fz,   f101.x, o0);      o1 = fmaf(fx*wy0*fz,   f101.y, o1);
        o0 = fmaf(fx*fy*wz0,   f110.x, o0);      o1 = fmaf(fx*fy*wz0,   f110.y, o1);
        o0 = fmaf(fx*fy*fz,    f111.x, o0);      o1 = fmaf(fx*fy*fz,    f111.y, o1);

        featws[(size_t)l * NPTS + p] = packbf(o0, o1);
    } else {
        const int rank = xcd * tailn + (s - 1152);
        if (rank < ncb) {
            // -------- oct build, 2 cells/thread via x-parity pair-loads ----
            const int gt = rank * 256 + tid;
            if (gt >= qi.toff[NQ]) return;

            int l = 0;
            #pragma unroll
            for (int j = 1; j < NQ; ++j) if (gt >= qi.toff[j]) l = j;
            const int t   = gt - qi.toff[l];
            const int D   = qi.dim[l];
            const int DD  = D*D;
            const int off = qi.off[l];

            const int x  = 2 * (t / DD);            // even slab
            const int yz = t % DD;
            const unsigned y = (unsigned)(yz / D);
            const unsigned z = (unsigned)(yz % D);

            const float4* __restrict__ emb4 = (const float4*)emb;
            const unsigned base4 = (unsigned)l * (TBL >> 1);
            const unsigned hy0 = y*2654435761u, hy1 = (y+1u)*2654435761u;
            const unsigned hz0 = z*805459861u,  hz1 = (z+1u)*805459861u;
            const unsigned ux = (unsigned)x;

            // 4 (y,z) corners; each pair-load yields slab x and slab x+1
            uint4 sx, sx1;
            {
                const unsigned h = (ux^hy0^hz0) & TMASK;
                const float4 p4 = emb4[base4 + (h >> 1)];
                sx.x  = (h&1) ? packbf(p4.z, p4.w) : packbf(p4.x, p4.y);
                sx1.x = (h&1) ? packbf(p4.x, p4.y) : packbf(p4.z, p4.w);
            }
            {
                const unsigned h = (ux^hy0^hz1) & TMASK;
                const float4 p4 = emb4[base4 + (h >> 1)];
                sx.y  = (h&1) ? packbf(p4.z, p4.w) : packbf(p4.x, p4.y);
                sx1.y = (h&1) ? packbf(p4.x, p4.y) : packbf(p4.z, p4.w);
            }
            {
                const unsigned h = (ux^hy1^hz0) & TMASK;
                const float4 p4 = emb4[base4 + (h >> 1)];
                sx.z  = (h&1) ? packbf(p4.z, p4.w) : packbf(p4.x, p4.y);
                sx1.z = (h&1) ? packbf(p4.x, p4.y) : packbf(p4.z, p4.w);
            }
            {
                const unsigned h = (ux^hy1^hz1) & TMASK;
                const float4 p4 = emb4[base4 + (h >> 1)];
                sx.w  = (h&1) ? packbf(p4.z, p4.w) : packbf(p4.x, p4.y);
                sx1.w = (h&1) ? packbf(p4.x, p4.y) : packbf(p4.z, p4.w);
            }

            // cell e(x): lo = slab x, hi = slab x+1
            // cell e(x-1): hi = slab x ; cell e(x+1): lo = slab x+1
            const int e = off + (x*D + (int)y)*D + (int)z;
            if (x < D) {
                oct[2*e]     = sx;
                oct[2*e + 1] = sx1;
            }
            if (x > 0)
                oct[2*(e - DD) + 1] = sx;
            if (x + 1 < D)
                oct[2*(e + DD)]     = sx1;
        } else if (rank == ncb) {
            // -------- weight/bias pack --------
            const int wid  = tid >> 6;
            const int lane = tid & 63;
            const int m16  = lane & 15;
            const int q    = lane >> 4;
            const unsigned char MAT[28] = {0,0,0,0, 1,1, 2,2,2,2, 3,3,3,3,3,3,3,3, 4,4,4,4,4,4,4,4, 5,5};
            const unsigned char K0 [28] = {0,0,0,0, 0,32, 0,0,0,0, 0,0,0,0,32,32,32,32, 0,0,0,0,32,32,32,32, 0,32};
            const unsigned char N0 [28] = {0,16,32,48, 0,0, 0,16,32,48, 0,16,32,48,0,16,32,48, 0,16,32,48,0,16,32,48, 0,0};
            #pragma unroll
            for (int s2 = 0; s2 < 28; ++s2) {
                if ((s2 & 3) == wid) {
                    const int mat = MAT[s2];
                    const float* src = mat==0?dw1 : mat==1?dw2 : mat==2?cw1 : mat==3?cw2 : mat==4?cw3 : cw4;
                    const int fan = (mat==1) ? 16 : (mat==5) ? 3 : 64;
                    const int k = (int)K0[s2] + q*8;
                    const int n = (int)N0[s2] + m16;
                    unsigned short u[8];
                    #pragma unroll
                    for (int j = 0; j < 8; ++j) {
                        float v = 0.f;
                        if (mat != 5 || n < 3) v = src[(k+j)*fan + n];
                        u[j] = f2bf(v);
                    }
                    unsigned* w32 = (unsigned*)(wpk + s2*512 + lane*8);
                    w32[0] = (unsigned)u[0] | ((unsigned)u[1] << 16);
                    w32[1] = (unsigned)u[2] | ((unsigned)u[3] << 16);
                    w32[2] = (unsigned)u[4] | ((unsigned)u[5] << 16);
                    w32[3] = (unsigned)u[6] | ((unsigned)u[7] << 16);
                }
            }
            {
                int t = tid;
                if      (t <  64) bpk[t] = db1[t];
                else if (t <  80) bpk[t] = db2[t-64];
                else if (t < 144) bpk[t] = cb1[t-80];
                else if (t < 208) bpk[t] = cb2[t-144];
            }
            if (tid < 80) {
                int t = tid + 208;
                if (t < 272) bpk[t] = cb3[t-208];
                else         bpk[t] = (t-272 < 3) ? cb4[t-272] : 0.f;
            }
        }
    }
}

// ---------------------------------------------------------------------------
// Kernel 2: oct consume (levels 0..6) + MFMA MLP chain. (unchanged from R5)
// ---------------------------------------------------------------------------
__global__ __launch_bounds__(512, 4) void mlp_mfma_k(
    const unsigned* __restrict__ featws,
    const uint4* __restrict__ oct,
    const float* __restrict__ coords,
    const unsigned short* __restrict__ wpk,
    const float* __restrict__ bpk,
    const float* __restrict__ dirs,
    float* __restrict__ out,
    ResArr res, QuadInfo qi)
{
    const int tid  = threadIdx.x;
    const int wid  = tid >> 6;          // 0..7
    const int lane = tid & 63;
    const int m16  = lane & 15;
    const int q    = lane >> 4;

    __shared__ __align__(16) unsigned short wlds[28 * 512];
    __shared__ float blds[288];
    __shared__ __align__(16) unsigned short actL[8 * 16 * 72]; // per-wave [16][64+8] bf16
    __shared__ unsigned featO[TPB * 7];                        // [pt][lvl 0..6], stride 7

    {
        uint4* dst = (uint4*)wlds;
        const uint4* srcv = (const uint4*)wpk;   // 1792 uint4
        #pragma unroll
        for (int j = 0; j < 4; ++j) {
            const int idx = j*512 + tid;
            if (idx < 1792) dst[idx] = srcv[idx];
        }
        if (tid < 288) blds[tid] = bpk[tid];
    }

    const int pbase = blockIdx.x * TPB;

    // ---- prefetch iter-0 global A-frag dwords (levels 7..15) ----
    unsigned g0, g1, g2, g3;
    {
        const int pg = pbase + wid*16 + m16;     // tile = wid at iter 0
        const int l0 = q*4;
        g0 = (l0+0 >= NQ) ? featws[(size_t)(l0+0) * NPTS + pg] : 0u;
        g1 = (l0+1 >= NQ) ? featws[(size_t)(l0+1) * NPTS + pg] : 0u;
        g2 = (l0+2 >= NQ) ? featws[(size_t)(l0+2) * NPTS + pg] : 0u;
        g3 = (l0+3 >= NQ) ? featws[(size_t)(l0+3) * NPTS + pg] : 0u;
    }

    // ---- oct consume: levels 0..6 for point pbase+tid ----
    {
        const int p = pbase + tid;
        const float cx = coords[3*p], cy = coords[3*p+1], cz = coords[3*p+2];
        #pragma unroll
        for (int l = 0; l < NQ; ++l) {
            const float r = res.r[l];
            const float px = cx*r, py = cy*r, pz = cz*r;
            const float fpx = floorf(px), fpy = floorf(py), fpz = floorf(pz);
            const float fx = px-fpx, fy = py-fpy, fz = pz-fpz;
            const int ix=(int)fpx, iy=(int)fpy, iz=(int)fpz;
            const int D = qi.dim[l];
            const int v0 = qi.off[l] + (ix*D + iy)*D + iz;
            const uint4 qA = oct[2*v0];
            const uint4 qB = oct[2*v0 + 1];
            const float wx0=1.f-fx, wy0=1.f-fy, wz0=1.f-fz;
            const float w000=wx0*wy0*wz0, w001=wx0*wy0*fz;
            const float w010=wx0*fy*wz0,  w011=wx0*fy*fz;
            const float w100=fx*wy0*wz0,  w101=fx*wy0*fz;
            const float w110=fx*fy*wz0,   w111=fx*fy*fz;
            float o0, o1;
            o0 = w000*blo(qA.x);              o1 = w000*bhi(qA.x);
            o0 = fmaf(w001, blo(qA.y), o0);   o1 = fmaf(w001, bhi(qA.y), o1);
            o0 = fmaf(w010, blo(qA.z), o0);   o1 = fmaf(w010, bhi(qA.z), o1);
            o0 = fmaf(w011, blo(qA.w), o0);   o1 = fmaf(w011, bhi(qA.w), o1);
            o0 = fmaf(w100, blo(qB.x), o0);   o1 = fmaf(w100, bhi(qB.x), o1);
            o0 = fmaf(w101, blo(qB.y), o0);   o1 = fmaf(w101, bhi(qB.y), o1);
            o0 = fmaf(w110, blo(qB.z), o0);   o1 = fmaf(w110, bhi(qB.z), o1);
            o0 = fmaf(w111, blo(qB.w), o0);   o1 = fmaf(w111, bhi(qB.w), o1);
            featO[tid*7 + l] = packbf(o0, o1);
        }
    }
    __syncthreads();

    unsigned short* aw = actL + wid*1152;     // 16 x 72
    const short8* wfr = (const short8*)wlds;  // B(s) = wfr[s*64 + lane]

    #pragma unroll 1
    for (int iter = 0; iter < 4; ++iter) {
        const int tile = wid + 8*iter;
        const int loc0 = tile*16;
        const int p0g  = pbase + loc0;

        // ---- prefetch next iter's global A-frag dwords ----
        unsigned n0 = 0u, n1 = 0u, n2 = 0u, n3 = 0u;
        if (iter < 3) {
            const int pg = pbase + (wid + 8*(iter+1))*16 + m16;
            const int l0 = q*4;
            n0 = (l0+0 >= NQ) ? featws[(size_t)(l0+0) * NPTS + pg] : 0u;
            n1 = (l0+1 >= NQ) ? featws[(size_t)(l0+1) * NPTS + pg] : 0u;
            n2 = (l0+2 >= NQ) ? featws[(size_t)(l0+2) * NPTS + pg] : 0u;
            n3 = (l0+3 >= NQ) ? featws[(size_t)(l0+3) * NPTS + pg] : 0u;
        }

        // ---- A-frag for density L1: levels q*4..q*4+3 of point p0g+m16 ----
        union { unsigned u[4]; short8 s; } af;
        {
            const int l0 = q*4;
            const int rowb = (loc0 + m16) * 7;
            af.u[0] = (l0+0 < NQ) ? featO[rowb + l0+0] : g0;
            af.u[1] = (l0+1 < NQ) ? featO[rowb + l0+1] : g1;
            af.u[2] = (l0+2 < NQ) ? featO[rowb + l0+2] : g2;
            af.u[3] = (l0+3 < NQ) ? featO[rowb + l0+3] : g3;
        }
        const short8 a0 = af.s;

        // ---- density L1: feat(32) -> 64, relu ----
        f32x4 acc[4];
        #pragma unroll
        for (int nc = 0; nc < 4; ++nc) {
            const float b = blds[nc*16 + m16];
            acc[nc] = (f32x4){b,b,b,b};
            acc[nc] = MFMA(a0, wfr[nc*64 + lane], acc[nc]);
        }
        #pragma unroll
        for (int nc = 0; nc < 4; ++nc)
            #pragma unroll
            for (int r = 0; r < 4; ++r)
                aw[(q*4+r)*72 + nc*16 + m16] = f2bf(fmaxf(acc[nc][r], 0.f));

        // ---- density L2: 64 -> 16 (no act) ----
        short8 ad0 = *(const short8*)(aw + m16*72 + q*8);
        short8 ad1 = *(const short8*)(aw + m16*72 + 32 + q*8);
        f32x4 dob;
        { const float b = blds[64 + m16]; dob = (f32x4){b,b,b,b}; }
        dob = MFMA(ad0, wfr[4*64 + lane], dob);
        dob = MFMA(ad1, wfr[5*64 + lane], dob);

        if (m16 == 0) {
            #pragma unroll
            for (int r = 0; r < 4; ++r) out[p0g + q*4 + r] = expf(dob[r]);
        }

        // ---- build inp = [SH(16) | dob(16)] ----
        #pragma unroll
        for (int r = 0; r < 4; ++r)
            aw[(q*4+r)*72 + 16 + m16] = f2bf(dob[r]);
        {
            const int pg = p0g + m16;
            const float dx0 = dirs[3*pg], dy0 = dirs[3*pg+1], dz0 = dirs[3*pg+2];
            const float inv = 1.f / sqrtf(dx0*dx0 + dy0*dy0 + dz0*dz0);
            float x = dx0*inv, y = dy0*inv, z = dz0*inv;
            x = ((x+1.f)*0.5f)*2.f - 1.f;
            y = ((y+1.f)*0.5f)*2.f - 1.f;
            z = ((z+1.f)*0.5f)*2.f - 1.f;
            float s0, s1, s2, s3;
            switch (q) {
            case 0: s0 = 0.28209479177387814f;
                    s1 = -0.48860251190291987f*y;
                    s2 =  0.48860251190291987f*z;
                    s3 = -0.48860251190291987f*x; break;
            case 1: s0 =  1.0925484305920792f*x*y;
                    s1 = -1.0925484305920792f*y*z;
                    s2 =  0.94617469575756f*z*z - 0.31539156525252f;
                    s3 = -1.0925484305920792f*x*z; break;
            case 2: s0 =  0.5462742152960396f*(x*x - y*y);
                    s1 =  0.5900435899266435f*y*(-3.f*x*x + y*y);
                    s2 =  2.890611442640554f*x*y*z;
                    s3 =  0.4570457994644657f*y*(1.f - 5.f*z*z); break;
            default:s0 =  0.3731763325901154f*z*(5.f*z*z - 3.f);
                    s1 =  0.4570457994644657f*x*(1.f - 5.f*z*z);
                    s2 =  1.445305721320277f*z*(x*x - y*y);
                    s3 =  0.5900435899266435f*x*(x*x - 3.f*y*y); break;
            }
            unsigned* ip = (unsigned*)(aw + m16*72 + q*4);
            ip[0] = packbf(s0, s1);
            ip[1] = packbf(s2, s3);
        }

        // ---- color L1: inp(32) -> 64, relu ----
        short8 ac0 = *(const short8*)(aw + m16*72 + q*8);
        #pragma unroll
        for (int nc = 0; nc < 4; ++nc) {
            const float b = blds[80 + nc*16 + m16];
            acc[nc] = (f32x4){b,b,b,b};
            acc[nc] = MFMA(ac0, wfr[(6+nc)*64 + lane], acc[nc]);
        }
        #pragma unroll
        for (int nc = 0; nc < 4; ++nc)
            #pragma unroll
            for (int r = 0; r < 4; ++r)
                aw[(q*4+r)*72 + nc*16 + m16] = f2bf(fmaxf(acc[nc][r], 0.f));

        // ---- color L2: 64 -> 64, relu ----
        short8 a20 = *(const short8*)(aw + m16*72 + q*8);
        short8 a21 = *(const short8*)(aw + m16*72 + 32 + q*8);
        #pragma unroll
        for (int nc = 0; nc < 4; ++nc) {
            const float b = blds[144 + nc*16 + m16];
            acc[nc] = (f32x4){b,b,b,b};
            acc[nc] = MFMA(a20, wfr[(10+nc)*64 + lane], acc[nc]);
            acc[nc] = MFMA(a21, wfr[(14+nc)*64 + lane], acc[nc]);
        }
        #pragma unroll
        for (int nc = 0; nc < 4; ++nc)
            #pragma unroll
            for (int r = 0; r < 4; ++r)
                aw[(q*4+r)*72 + nc*16 + m16] = f2bf(fmaxf(acc[nc][r], 0.f));

        // ---- color L3: 64 -> 64, relu ----
        short8 a30 = *(const short8*)(aw + m16*72 + q*8);
        short8 a31 = *(const short8*)(aw + m16*72 + 32 + q*8);
        #pragma unroll
        for (int nc = 0; nc < 4; ++nc) {
            const float b = blds[208 + nc*16 + m16];
            acc[nc] = (f32x4){b,b,b,b};
            acc[nc] = MFMA(a30, wfr[(18+nc)*64 + lane], acc[nc]);
            acc[nc] = MFMA(a31, wfr[(22+nc)*64 + lane], acc[nc]);
        }
        #pragma unroll
        for (int nc = 0; nc < 4; ++nc)
            #pragma unroll
            for (int r = 0; r < 4; ++r)
                aw[(q*4+r)*72 + nc*16 + m16] = f2bf(fmaxf(acc[nc][r], 0.f));

        // ---- color L4: 64 -> 3 (padded to 16), sigmoid ----
        short8 a40 = *(const short8*)(aw + m16*72 + q*8);
        short8 a41 = *(const short8*)(aw + m16*72 + 32 + q*8);
        f32x4 c4v;
        { const float b = blds[272 + m16]; c4v = (f32x4){b,b,b,b}; }
        c4v = MFMA(a40, wfr[26*64 + lane], c4v);
        c4v = MFMA(a41, wfr[27*64 + lane], c4v);
        if (m16 < 3) {
            #pragma unroll
            for (int r = 0; r < 4; ++r)
                out[NPTS + 3*(p0g + q*4 + r) + m16] = 1.f / (1.f + expf(-c4v[r]));
        }

        // rotate prefetch
        g0 = n0; g1 = n1; g2 = n2; g3 = n3;
    }
}

extern "C" void kernel_launch(void* const* d_in, const int* in_sizes, int n_in,
                              void* d_out, int out_size, void* d_ws, size_t ws_size,
                              hipStream_t stream)
{
    // RES must bit-match numpy: floor(16 * b**l) in f64, b = exp((ln512-ln16)/15).
    ResArr res;
    const double b = exp((log(512.0) - log(16.0)) / 15.0);
    for (int l = 0; l < NLVL; ++l)
        res.r[l] = (float)floor(16.0 * pow(b, (double)l));

    // oct arrays for levels 0..6: dim = res+1; build threads cover even slabs
    QuadInfo qi;
    int ncell = 0, nth = 0;
    for (int l = 0; l < NQ; ++l) {
        const int D = (int)res.r[l] + 1;
        qi.dim[l]  = D;
        qi.off[l]  = ncell;
        qi.toff[l] = nth;
        ncell += D*D*D;
        nth   += ((D + 1) / 2) * D * D;   // K = (D+1)/2 even-slab threads
    }
    qi.toff[NQ] = nth;                    // 277,105 build threads
    const int ncb   = (nth + 255) / 256;  // build blocks (~1083)
    const int tailn = (ncb + 1 + 7) / 8;  // tail slots per XCD
    const int smax  = 1152 + tailn;
    const int grid  = smax * 8;

    // ws: featws 16.8MB | oct (543,884*32B = 17.4MB) | wpk 28KB | bpk 1.2KB
    unsigned*       featws = (unsigned*)d_ws;
    uint4*          oct    = (uint4*)((char*)d_ws + (size_t)NLVL * NPTS * 4);
    unsigned short* wpk    = (unsigned short*)((char*)oct + (size_t)ncell * 32);
    float*          bpk    = (float*)((char*)wpk + 28 * 512 * 2);

    fused_encode_k<<<grid, 256, 0, stream>>>(
        (const float*)d_in[0],   // coords
        (const float*)d_in[2],   // embeddings
        oct, featws,
        (const float*)d_in[3],  (const float*)d_in[4],
        (const float*)d_in[5],  (const float*)d_in[6],
        (const float*)d_in[7],  (const float*)d_in[8],
        (const float*)d_in[9],  (const float*)d_in[10],
        (const float*)d_in[11], (const float*)d_in[12],
        (const float*)d_in[13], (const float*)d_in[14],
        wpk, bpk, res, qi, ncb, tailn);

    mlp_mfma_k<<<NPTS/TPB, 512, 0, stream>>>(
        featws, oct,
        (const float*)d_in[0],   // coords
        wpk, bpk,
        (const float*)d_in[1],   // directions
        (float*)d_out,
        res, qi);
}

// Round 7
// 223.695 us; speedup vs baseline: 1.0158x; 1.0158x over previous
//
#include <hip/hip_runtime.h>
#include <cmath>

#define NPTS 262144
#define NLVL 16
#define TBL  524288u
#define TMASK 524287u
#define TPB  512   // points per block (k2): 8 waves, 2 blocks/CU
#define NQ   7     // levels 0..6 oct-densified

typedef __attribute__((ext_vector_type(8))) short short8;
typedef __attribute__((ext_vector_type(4))) float f32x4;

struct ResArr { float r[NLVL]; };
struct QuadInfo { int off[NQ]; int dim[NQ]; int toff[NQ+1]; }; // off: oct entries; toff: build-thread prefix

__device__ __forceinline__ unsigned short f2bf(float f) {
    union { float f; unsigned u; } v; v.f = f;
    unsigned r = v.u + 0x7FFFu + ((v.u >> 16) & 1u);   // RNE
    return (unsigned short)(r >> 16);
}
__device__ __forceinline__ float blo(unsigned u) {
    union { unsigned v; float f; } x; x.v = u << 16; return x.f;
}
__device__ __forceinline__ float bhi(unsigned u) {
    union { unsigned v; float f; } x; x.v = u & 0xffff0000u; return x.f;
}
__device__ __forceinline__ unsigned packbf(float a, float b) {
    return (unsigned)f2bf(a) | ((unsigned)f2bf(b) << 16);
}

#define MFMA(a,b,c) __builtin_amdgcn_mfma_f32_16x16x32_bf16((a),(b),(c),0,0,0)

// ---------------------------------------------------------------------------
// Kernel 1 (fused): hash-grid encode for levels 7..15 + oct BUILD for levels
// 0..6 + weight/bias pack, one request stream.
// R7: hashed-path coords staged through LDS (3 coalesced dword loads/thread
// = 12 req/wave vs 36 for stride-12 scalar reads; LDS read 3t%32 = 2-way
// conflict = free). -0.11M req/XCD (~5% of the stream).
// ---------------------------------------------------------------------------
__global__ __launch_bounds__(256) void fused_encode_k(
    const float* __restrict__ coords,
    const float* __restrict__ emb,
    uint4* __restrict__ oct,
    unsigned* __restrict__ featws,
    const float* __restrict__ dw1, const float* __restrict__ db1,
    const float* __restrict__ dw2, const float* __restrict__ db2,
    const float* __restrict__ cw1, const float* __restrict__ cb1,
    const float* __restrict__ cw2, const float* __restrict__ cb2,
    const float* __restrict__ cw3, const float* __restrict__ cb3,
    const float* __restrict__ cw4, const float* __restrict__ cb4,
    unsigned short* __restrict__ wpk, float* __restrict__ bpk,
    ResArr res, QuadInfo qi, int ncb, int tailn)
{
    const int tid = threadIdx.x;
    const int b   = blockIdx.x;
    const int xcd = b & 7;
    const int s   = b >> 3;

    __shared__ float cstage[768];

    if (s < 1152) {
        // -------- hashed path (levels 7..15), x-parity pairing --------
        int l, pblk;
        if (s < 1024) {
            l = 7 + xcd;
            pblk = s * 256;
        } else {
            l = 15;
            pblk = xcd * 32768 + (s - 1024) * 256;
        }
        const int p = pblk + tid;

        // coalesced coords staging: 768 contiguous dwords
        cstage[tid]       = coords[3*pblk + tid];
        cstage[256 + tid] = coords[3*pblk + 256 + tid];
        cstage[512 + tid] = coords[3*pblk + 512 + tid];
        __syncthreads();
        const float cx = cstage[3*tid], cy = cstage[3*tid+1], cz = cstage[3*tid+2];

        const float r = res.r[l];
        const float px = cx*r, py = cy*r, pz = cz*r;
        const float fpx = floorf(px), fpy = floorf(py), fpz = floorf(pz);
        const float fx = px-fpx, fy = py-fpy, fz = pz-fpz;
        const unsigned ix=(unsigned)fpx, iy=(unsigned)fpy, iz=(unsigned)fpz;
        const unsigned hy0=iy*2654435761u, hy1=(iy+1u)*2654435761u;
        const unsigned hz0=iz*805459861u,  hz1=(iz+1u)*805459861u;
        const unsigned base  = (unsigned)l * TBL;          // float2 units
        const unsigned base4 = (unsigned)l * (TBL >> 1);   // float4 units
        const float2* __restrict__ emb2 = (const float2*)emb;
        const float4* __restrict__ emb4 = (const float4*)emb;

        const unsigned m = ix ^ (ix + 1u);                 // 1 iff ix even
        const unsigned h00 = (ix^hy0^hz0) & TMASK;
        const unsigned h01 = (ix^hy0^hz1) & TMASK;
        const unsigned h10 = (ix^hy1^hz0) & TMASK;
        const unsigned h11 = (ix^hy1^hz1) & TMASK;

        // pair loads: float4 at h>>1 = entries {h&~1, h|1}
        const float4 p00 = emb4[base4 + (h00 >> 1)];
        const float4 p01 = emb4[base4 + (h01 >> 1)];
        const float4 p10 = emb4[base4 + (h10 >> 1)];
        const float4 p11 = emb4[base4 + (h11 >> 1)];

        // x0 corner = half selected by h&1; x1 corner = other half (iff m==1)
        float2 f000, f001, f010, f011, f100, f101, f110, f111;
        f000.x = (h00&1) ? p00.z : p00.x;  f000.y = (h00&1) ? p00.w : p00.y;
        f001.x = (h01&1) ? p01.z : p01.x;  f001.y = (h01&1) ? p01.w : p01.y;
        f010.x = (h10&1) ? p10.z : p10.x;  f010.y = (h10&1) ? p10.w : p10.y;
        f011.x = (h11&1) ? p11.z : p11.x;  f011.y = (h11&1) ? p11.w : p11.y;
        f100.x = (h00&1) ? p00.x : p00.z;  f100.y = (h00&1) ? p00.y : p00.w;
        f101.x = (h01&1) ? p01.x : p01.z;  f101.y = (h01&1) ? p01.y : p01.w;
        f110.x = (h10&1) ? p10.x : p10.z;  f110.y = (h10&1) ? p10.y : p10.w;
        f111.x = (h11&1) ? p11.x : p11.z;  f111.y = (h11&1) ? p11.y : p11.w;

        if (m != 1u) {
            // odd-x lanes: true x1 corners are h^m, not in the pair
            f100 = emb2[base + ((h00 ^ m) & TMASK)];
            f101 = emb2[base + ((h01 ^ m) & TMASK)];
            f110 = emb2[base + ((h10 ^ m) & TMASK)];
            f111 = emb2[base + ((h11 ^ m) & TMASK)];
        }

        const float wx0=1.f-fx, wy0=1.f-fy, wz0=1.f-fz;
        float o0, o1;
        o0 = wx0*wy0*wz0*f000.x;                 o1 = wx0*wy0*wz0*f000.y;
        o0 = fmaf(wx0*wy0*fz,  f001.x, o0);      o1 = fmaf(wx0*wy0*fz,  f001.y, o1);
        o0 = fmaf(wx0*fy*wz0,  f010.x, o0);      o1 = fmaf(wx0*fy*wz0,  f010.y, o1);
        o0 = fmaf(wx0*fy*fz,   f011.x, o0);      o1 = fmaf(wx0*fy*fz,   f011.y, o1);
        o0 = fmaf(fx*wy0*wz0,  f100.x, o0);      o1 = fmaf(fx*wy0*wz0,  f100.y, o1);
        o0 = fmaf(fx*wy0*fz,   f101.x, o0);      o1 = fmaf(fx*wy0*fz,   f101.y, o1);
        o0 = fmaf(fx*fy*wz0,   f110.x, o0);      o1 = fmaf(fx*fy*wz0,   f110.y, o1);
        o0 = fmaf(fx*fy*fz,    f111.x, o0);      o1 = fmaf(fx*fy*fz,    f111.y, o1);

        featws[(size_t)l * NPTS + p] = packbf(o0, o1);
    } else {
        const int rank = xcd * tailn + (s - 1152);
        if (rank < ncb) {
            // -------- oct build, 2 cells/thread via x-parity pair-loads ----
            const int gt = rank * 256 + tid;
            if (gt >= qi.toff[NQ]) return;

            int l = 0;
            #pragma unroll
            for (int j = 1; j < NQ; ++j) if (gt >= qi.toff[j]) l = j;
            const int t   = gt - qi.toff[l];
            const int D   = qi.dim[l];
            const int DD  = D*D;
            const int off = qi.off[l];

            const int x  = 2 * (t / DD);            // even slab
            const int yz = t % DD;
            const unsigned y = (unsigned)(yz / D);
            const unsigned z = (unsigned)(yz % D);

            const float4* __restrict__ emb4 = (const float4*)emb;
            const unsigned base4 = (unsigned)l * (TBL >> 1);
            const unsigned hy0 = y*2654435761u, hy1 = (y+1u)*2654435761u;
            const unsigned hz0 = z*805459861u,  hz1 = (z+1u)*805459861u;
            const unsigned ux = (unsigned)x;

            // 4 (y,z) corners; each pair-load yields slab x and slab x+1
            uint4 sx, sx1;
            {
                const unsigned h = (ux^hy0^hz0) & TMASK;
                const float4 p4 = emb4[base4 + (h >> 1)];
                sx.x  = (h&1) ? packbf(p4.z, p4.w) : packbf(p4.x, p4.y);
                sx1.x = (h&1) ? packbf(p4.x, p4.y) : packbf(p4.z, p4.w);
            }
            {
                const unsigned h = (ux^hy0^hz1) & TMASK;
                const float4 p4 = emb4[base4 + (h >> 1)];
                sx.y  = (h&1) ? packbf(p4.z, p4.w) : packbf(p4.x, p4.y);
                sx1.y = (h&1) ? packbf(p4.x, p4.y) : packbf(p4.z, p4.w);
            }
            {
                const unsigned h = (ux^hy1^hz0) & TMASK;
                const float4 p4 = emb4[base4 + (h >> 1)];
                sx.z  = (h&1) ? packbf(p4.z, p4.w) : packbf(p4.x, p4.y);
                sx1.z = (h&1) ? packbf(p4.x, p4.y) : packbf(p4.z, p4.w);
            }
            {
                const unsigned h = (ux^hy1^hz1) & TMASK;
                const float4 p4 = emb4[base4 + (h >> 1)];
                sx.w  = (h&1) ? packbf(p4.z, p4.w) : packbf(p4.x, p4.y);
                sx1.w = (h&1) ? packbf(p4.x, p4.y) : packbf(p4.z, p4.w);
            }

            // cell e(x): lo = slab x, hi = slab x+1
            // cell e(x-1): hi = slab x ; cell e(x+1): lo = slab x+1
            const int e = off + (x*D + (int)y)*D + (int)z;
            if (x < D) {
                oct[2*e]     = sx;
                oct[2*e + 1] = sx1;
            }
            if (x > 0)
                oct[2*(e - DD) + 1] = sx;
            if (x + 1 < D)
                oct[2*(e + DD)]     = sx1;
        } else if (rank == ncb) {
            // -------- weight/bias pack --------
            const int wid  = tid >> 6;
            const int lane = tid & 63;
            const int m16  = lane & 15;
            const int q    = lane >> 4;
            const unsigned char MAT[28] = {0,0,0,0, 1,1, 2,2,2,2, 3,3,3,3,3,3,3,3, 4,4,4,4,4,4,4,4, 5,5};
            const unsigned char K0 [28] = {0,0,0,0, 0,32, 0,0,0,0, 0,0,0,0,32,32,32,32, 0,0,0,0,32,32,32,32, 0,32};
            const unsigned char N0 [28] = {0,16,32,48, 0,0, 0,16,32,48, 0,16,32,48,0,16,32,48, 0,16,32,48,0,16,32,48, 0,0};
            #pragma unroll
            for (int s2 = 0; s2 < 28; ++s2) {
                if ((s2 & 3) == wid) {
                    const int mat = MAT[s2];
                    const float* src = mat==0?dw1 : mat==1?dw2 : mat==2?cw1 : mat==3?cw2 : mat==4?cw3 : cw4;
                    const int fan = (mat==1) ? 16 : (mat==5) ? 3 : 64;
                    const int k = (int)K0[s2] + q*8;
                    const int n = (int)N0[s2] + m16;
                    unsigned short u[8];
                    #pragma unroll
                    for (int j = 0; j < 8; ++j) {
                        float v = 0.f;
                        if (mat != 5 || n < 3) v = src[(k+j)*fan + n];
                        u[j] = f2bf(v);
                    }
                    unsigned* w32 = (unsigned*)(wpk + s2*512 + lane*8);
                    w32[0] = (unsigned)u[0] | ((unsigned)u[1] << 16);
                    w32[1] = (unsigned)u[2] | ((unsigned)u[3] << 16);
                    w32[2] = (unsigned)u[4] | ((unsigned)u[5] << 16);
                    w32[3] = (unsigned)u[6] | ((unsigned)u[7] << 16);
                }
            }
            {
                int t = tid;
                if      (t <  64) bpk[t] = db1[t];
                else if (t <  80) bpk[t] = db2[t-64];
                else if (t < 144) bpk[t] = cb1[t-80];
                else if (t < 208) bpk[t] = cb2[t-144];
            }
            if (tid < 80) {
                int t = tid + 208;
                if (t < 272) bpk[t] = cb3[t-208];
                else         bpk[t] = (t-272 < 3) ? cb4[t-272] : 0.f;
            }
        }
    }
}

// ---------------------------------------------------------------------------
// Kernel 2: oct consume (levels 0..6) + MFMA MLP chain.
// R7: coords AND dirs staged through LDS coalesced (saves ~0.13M scattered
// req/XCD). LDS ~74.9KB -> still 2 blocks/CU (16 waves).
// ---------------------------------------------------------------------------
__global__ __launch_bounds__(512, 4) void mlp_mfma_k(
    const unsigned* __restrict__ featws,
    const uint4* __restrict__ oct,
    const float* __restrict__ coords,
    const unsigned short* __restrict__ wpk,
    const float* __restrict__ bpk,
    const float* __restrict__ dirs,
    float* __restrict__ out,
    ResArr res, QuadInfo qi)
{
    const int tid  = threadIdx.x;
    const int wid  = tid >> 6;          // 0..7
    const int lane = tid & 63;
    const int m16  = lane & 15;
    const int q    = lane >> 4;

    __shared__ __align__(16) unsigned short wlds[28 * 512];
    __shared__ float blds[288];
    __shared__ __align__(16) unsigned short actL[8 * 16 * 72]; // per-wave [16][64+8] bf16
    __shared__ unsigned featO[TPB * 7];                        // [pt][lvl 0..6], stride 7
    __shared__ float cst[TPB * 3];                             // staged coords
    __shared__ float dstg[TPB * 3];                            // staged dirs

    const int pbase = blockIdx.x * TPB;

    {
        uint4* dst = (uint4*)wlds;
        const uint4* srcv = (const uint4*)wpk;   // 1792 uint4
        #pragma unroll
        for (int j = 0; j < 4; ++j) {
            const int idx = j*512 + tid;
            if (idx < 1792) dst[idx] = srcv[idx];
        }
        if (tid < 288) blds[tid] = bpk[tid];
        #pragma unroll
        for (int j = 0; j < 3; ++j) {
            cst [j*512 + tid] = coords[3*pbase + j*512 + tid];
            dstg[j*512 + tid] = dirs  [3*pbase + j*512 + tid];
        }
    }
    __syncthreads();

    // ---- prefetch iter-0 global A-frag dwords (levels 7..15) ----
    unsigned g0, g1, g2, g3;
    {
        const int pg = pbase + wid*16 + m16;     // tile = wid at iter 0
        const int l0 = q*4;
        g0 = (l0+0 >= NQ) ? featws[(size_t)(l0+0) * NPTS + pg] : 0u;
        g1 = (l0+1 >= NQ) ? featws[(size_t)(l0+1) * NPTS + pg] : 0u;
        g2 = (l0+2 >= NQ) ? featws[(size_t)(l0+2) * NPTS + pg] : 0u;
        g3 = (l0+3 >= NQ) ? featws[(size_t)(l0+3) * NPTS + pg] : 0u;
    }

    // ---- oct consume: levels 0..6 for point pbase+tid ----
    {
        const float cx = cst[3*tid], cy = cst[3*tid+1], cz = cst[3*tid+2];
        #pragma unroll
        for (int l = 0; l < NQ; ++l) {
            const float r = res.r[l];
            const float px = cx*r, py = cy*r, pz = cz*r;
            const float fpx = floorf(px), fpy = floorf(py), fpz = floorf(pz);
            const float fx = px-fpx, fy = py-fpy, fz = pz-fpz;
            const int ix=(int)fpx, iy=(int)fpy, iz=(int)fpz;
            const int D = qi.dim[l];
            const int v0 = qi.off[l] + (ix*D + iy)*D + iz;
            const uint4 qA = oct[2*v0];
            const uint4 qB = oct[2*v0 + 1];
            const float wx0=1.f-fx, wy0=1.f-fy, wz0=1.f-fz;
            const float w000=wx0*wy0*wz0, w001=wx0*wy0*fz;
            const float w010=wx0*fy*wz0,  w011=wx0*fy*fz;
            const float w100=fx*wy0*wz0,  w101=fx*wy0*fz;
            const float w110=fx*fy*wz0,   w111=fx*fy*fz;
            float o0, o1;
            o0 = w000*blo(qA.x);              o1 = w000*bhi(qA.x);
            o0 = fmaf(w001, blo(qA.y), o0);   o1 = fmaf(w001, bhi(qA.y), o1);
            o0 = fmaf(w010, blo(qA.z), o0);   o1 = fmaf(w010, bhi(qA.z), o1);
            o0 = fmaf(w011, blo(qA.w), o0);   o1 = fmaf(w011, bhi(qA.w), o1);
            o0 = fmaf(w100, blo(qB.x), o0);   o1 = fmaf(w100, bhi(qB.x), o1);
            o0 = fmaf(w101, blo(qB.y), o0);   o1 = fmaf(w101, bhi(qB.y), o1);
            o0 = fmaf(w110, blo(qB.z), o0);   o1 = fmaf(w110, bhi(qB.z), o1);
            o0 = fmaf(w111, blo(qB.w), o0);   o1 = fmaf(w111, bhi(qB.w), o1);
            featO[tid*7 + l] = packbf(o0, o1);
        }
    }
    __syncthreads();

    unsigned short* aw = actL + wid*1152;     // 16 x 72
    const short8* wfr = (const short8*)wlds;  // B(s) = wfr[s*64 + lane]

    #pragma unroll 1
    for (int iter = 0; iter < 4; ++iter) {
        const int tile = wid + 8*iter;
        const int loc0 = tile*16;
        const int p0g  = pbase + loc0;

        // ---- prefetch next iter's global A-frag dwords ----
        unsigned n0 = 0u, n1 = 0u, n2 = 0u, n3 = 0u;
        if (iter < 3) {
            const int pg = pbase + (wid + 8*(iter+1))*16 + m16;
            const int l0 = q*4;
            n0 = (l0+0 >= NQ) ? featws[(size_t)(l0+0) * NPTS + pg] : 0u;
            n1 = (l0+1 >= NQ) ? featws[(size_t)(l0+1) * NPTS + pg] : 0u;
            n2 = (l0+2 >= NQ) ? featws[(size_t)(l0+2) * NPTS + pg] : 0u;
            n3 = (l0+3 >= NQ) ? featws[(size_t)(l0+3) * NPTS + pg] : 0u;
        }

        // ---- A-frag for density L1: levels q*4..q*4+3 of point p0g+m16 ----
        union { unsigned u[4]; short8 s; } af;
        {
            const int l0 = q*4;
            const int rowb = (loc0 + m16) * 7;
            af.u[0] = (l0+0 < NQ) ? featO[rowb + l0+0] : g0;
            af.u[1] = (l0+1 < NQ) ? featO[rowb + l0+1] : g1;
            af.u[2] = (l0+2 < NQ) ? featO[rowb + l0+2] : g2;
            af.u[3] = (l0+3 < NQ) ? featO[rowb + l0+3] : g3;
        }
        const short8 a0 = af.s;

        // ---- density L1: feat(32) -> 64, relu ----
        f32x4 acc[4];
        #pragma unroll
        for (int nc = 0; nc < 4; ++nc) {
            const float b = blds[nc*16 + m16];
            acc[nc] = (f32x4){b,b,b,b};
            acc[nc] = MFMA(a0, wfr[nc*64 + lane], acc[nc]);
        }
        #pragma unroll
        for (int nc = 0; nc < 4; ++nc)
            #pragma unroll
            for (int r = 0; r < 4; ++r)
                aw[(q*4+r)*72 + nc*16 + m16] = f2bf(fmaxf(acc[nc][r], 0.f));

        // ---- density L2: 64 -> 16 (no act) ----
        short8 ad0 = *(const short8*)(aw + m16*72 + q*8);
        short8 ad1 = *(const short8*)(aw + m16*72 + 32 + q*8);
        f32x4 dob;
        { const float b = blds[64 + m16]; dob = (f32x4){b,b,b,b}; }
        dob = MFMA(ad0, wfr[4*64 + lane], dob);
        dob = MFMA(ad1, wfr[5*64 + lane], dob);

        if (m16 == 0) {
            #pragma unroll
            for (int r = 0; r < 4; ++r) out[p0g + q*4 + r] = expf(dob[r]);
        }

        // ---- build inp = [SH(16) | dob(16)] ----
        #pragma unroll
        for (int r = 0; r < 4; ++r)
            aw[(q*4+r)*72 + 16 + m16] = f2bf(dob[r]);
        {
            const int lm = loc0 + m16;
            const float dx0 = dstg[3*lm], dy0 = dstg[3*lm+1], dz0 = dstg[3*lm+2];
            const float inv = 1.f / sqrtf(dx0*dx0 + dy0*dy0 + dz0*dz0);
            float x = dx0*inv, y = dy0*inv, z = dz0*inv;
            x = ((x+1.f)*0.5f)*2.f - 1.f;
            y = ((y+1.f)*0.5f)*2.f - 1.f;
            z = ((z+1.f)*0.5f)*2.f - 1.f;
            float s0, s1, s2, s3;
            switch (q) {
            case 0: s0 = 0.28209479177387814f;
                    s1 = -0.48860251190291987f*y;
                    s2 =  0.48860251190291987f*z;
                    s3 = -0.48860251190291987f*x; break;
            case 1: s0 =  1.0925484305920792f*x*y;
                    s1 = -1.0925484305920792f*y*z;
                    s2 =  0.94617469575756f*z*z - 0.31539156525252f;
                    s3 = -1.0925484305920792f*x*z; break;
            case 2: s0 =  0.5462742152960396f*(x*x - y*y);
                    s1 =  0.5900435899266435f*y*(-3.f*x*x + y*y);
                    s2 =  2.890611442640554f*x*y*z;
                    s3 =  0.4570457994644657f*y*(1.f - 5.f*z*z); break;
            default:s0 =  0.3731763325901154f*z*(5.f*z*z - 3.f);
                    s1 =  0.4570457994644657f*x*(1.f - 5.f*z*z);
                    s2 =  1.445305721320277f*z*(x*x - y*y);
                    s3 =  0.5900435899266435f*x*(x*x - 3.f*y*y); break;
            }
            unsigned* ip = (unsigned*)(aw + m16*72 + q*4);
            ip[0] = packbf(s0, s1);
            ip[1] = packbf(s2, s3);
        }

        // ---- color L1: inp(32) -> 64, relu ----
        short8 ac0 = *(const short8*)(aw + m16*72 + q*8);
        #pragma unroll
        for (int nc = 0; nc < 4; ++nc) {
            const float b = blds[80 + nc*16 + m16];
            acc[nc] = (f32x4){b,b,b,b};
            acc[nc] = MFMA(ac0, wfr[(6+nc)*64 + lane], acc[nc]);
        }
        #pragma unroll
        for (int nc = 0; nc < 4; ++nc)
            #pragma unroll
            for (int r = 0; r < 4; ++r)
                aw[(q*4+r)*72 + nc*16 + m16] = f2bf(fmaxf(acc[nc][r], 0.f));

        // ---- color L2: 64 -> 64, relu ----
        short8 a20 = *(const short8*)(aw + m16*72 + q*8);
        short8 a21 = *(const short8*)(aw + m16*72 + 32 + q*8);
        #pragma unroll
        for (int nc = 0; nc < 4; ++nc) {
            const float b = blds[144 + nc*16 + m16];
            acc[nc] = (f32x4){b,b,b,b};
            acc[nc] = MFMA(a20, wfr[(10+nc)*64 + lane], acc[nc]);
            acc[nc] = MFMA(a21, wfr[(14+nc)*64 + lane], acc[nc]);
        }
        #pragma unroll
        for (int nc = 0; nc < 4; ++nc)
            #pragma unroll
            for (int r = 0; r < 4; ++r)
                aw[(q*4+r)*72 + nc*16 + m16] = f2bf(fmaxf(acc[nc][r], 0.f));

        // ---- color L3: 64 -> 64, relu ----
        short8 a30 = *(const short8*)(aw + m16*72 + q*8);
        short8 a31 = *(const short8*)(aw + m16*72 + 32 + q*8);
        #pragma unroll
        for (int nc = 0; nc < 4; ++nc) {
            const float b = blds[208 + nc*16 + m16];
            acc[nc] = (f32x4){b,b,b,b};
            acc[nc] = MFMA(a30, wfr[(18+nc)*64 + lane], acc[nc]);
            acc[nc] = MFMA(a31, wfr[(22+nc)*64 + lane], acc[nc]);
        }
        #pragma unroll
        for (int nc = 0; nc < 4; ++nc)
            #pragma unroll
            for (int r = 0; r < 4; ++r)
                aw[(q*4+r)*72 + nc*16 + m16] = f2bf(fmaxf(acc[nc][r], 0.f));

        // ---- color L4: 64 -> 3 (padded to 16), sigmoid ----
        short8 a40 = *(const short8*)(aw + m16*72 + q*8);
        short8 a41 = *(const short8*)(aw + m16*72 + 32 + q*8);
        f32x4 c4v;
        { const float b = blds[272 + m16]; c4v = (f32x4){b,b,b,b}; }
        c4v = MFMA(a40, wfr[26*64 + lane], c4v);
        c4v = MFMA(a41, wfr[27*64 + lane], c4v);
        if (m16 < 3) {
            #pragma unroll
            for (int r = 0; r < 4; ++r)
                out[NPTS + 3*(p0g + q*4 + r) + m16] = 1.f / (1.f + expf(-c4v[r]));
        }

        // rotate prefetch
        g0 = n0; g1 = n1; g2 = n2; g3 = n3;
    }
}

extern "C" void kernel_launch(void* const* d_in, const int* in_sizes, int n_in,
                              void* d_out, int out_size, void* d_ws, size_t ws_size,
                              hipStream_t stream)
{
    // RES must bit-match numpy: floor(16 * b**l) in f64, b = exp((ln512-ln16)/15).
    ResArr res;
    const double b = exp((log(512.0) - log(16.0)) / 15.0);
    for (int l = 0; l < NLVL; ++l)
        res.r[l] = (float)floor(16.0 * pow(b, (double)l));

    // oct arrays for levels 0..6: dim = res+1; build threads cover even slabs
    QuadInfo qi;
    int ncell = 0, nth = 0;
    for (int l = 0; l < NQ; ++l) {
        const int D = (int)res.r[l] + 1;
        qi.dim[l]  = D;
        qi.off[l]  = ncell;
        qi.toff[l] = nth;
        ncell += D*D*D;
        nth   += ((D + 1) / 2) * D * D;   // K = (D+1)/2 even-slab threads
    }
    qi.toff[NQ] = nth;                    // build threads
    const int ncb   = (nth + 255) / 256;  // build blocks
    const int tailn = (ncb + 1 + 7) / 8;  // tail slots per XCD
    const int smax  = 1152 + tailn;
    const int grid  = smax * 8;

    // ws: featws 16.8MB | oct (543,884*32B = 17.4MB) | wpk 28KB | bpk 1.2KB
    unsigned*       featws = (unsigned*)d_ws;
    uint4*          oct    = (uint4*)((char*)d_ws + (size_t)NLVL * NPTS * 4);
    unsigned short* wpk    = (unsigned short*)((char*)oct + (size_t)ncell * 32);
    float*          bpk    = (float*)((char*)wpk + 28 * 512 * 2);

    fused_encode_k<<<grid, 256, 0, stream>>>(
        (const float*)d_in[0],   // coords
        (const float*)d_in[2],   // embeddings
        oct, featws,
        (const float*)d_in[3],  (const float*)d_in[4],
        (const float*)d_in[5],  (const float*)d_in[6],
        (const float*)d_in[7],  (const float*)d_in[8],
        (const float*)d_in[9],  (const float*)d_in[10],
        (const float*)d_in[11], (const float*)d_in[12],
        (const float*)d_in[13], (const float*)d_in[14],
        wpk, bpk, res, qi, ncb, tailn);

    mlp_mfma_k<<<NPTS/TPB, 512, 0, stream>>>(
        featws, oct,
        (const float*)d_in[0],   // coords
        wpk, bpk,
        (const float*)d_in[1],   // directions
        (float*)d_out,
        res, qi);
}